// Round 12
// baseline (2137.319 us; speedup 1.0000x reference)
//
#include <hip/hip_runtime.h>
#include <math.h>

// Problem constants: faces (13776,3) int32, vertices (2,6890,3) f32, G=32.
#define GRD 32
#define P (GRD*GRD*GRD)      // 32768 points per mesh
#define NP (2*P)             // 65536 total points
#define NV 6890
#define NF 13776
#define NSPLIT 4
#define FC (NF / NSPLIT)     // 3444 exactly (even -> unroll-by-2 safe)

__device__ __forceinline__ float safef(float x) {
    // reference _safe: |x|>1e-12 ? x : (x>=0 ? 1e-12 : -1e-12)
    float tiny = (x >= 0.0f) ? 1e-12f : -1e-12f;
    return fabsf(x) > 1e-12f ? x : tiny;
}

// precise-enough atan2 (err ~5e-7 rad), used only 4x per point in the final kernel
__device__ __forceinline__ float atan2_fast(float y, float x) {
    const float ay = fabsf(y), ax = fabsf(x);
    const float mn = fminf(ay, ax);
    const float mx = fmaxf(fmaxf(ay, ax), 1e-37f);
    const float hyp2 = fmaf(y, y, x * x);
    const float L = __builtin_amdgcn_sqrtf(hyp2);
    const float u = mn * __builtin_amdgcn_rcpf(fmaxf(mx + L, 1e-37f)); // tan(theta/2)
    const float z = u * u;
    float pl = fmaf(1.610748899076e-1f, z, -2.775537120640e-1f);
    pl = fmaf(pl, z, 3.995542129560e-1f);
    pl = fmaf(pl, z, -6.666589830780e-1f);
    float a = fmaf(pl * z, u, u + u);                 // atan(mn/mx)
    a = (ay > ax) ? (1.57079632679489662f - a) : a;
    a = (x < 0.0f) ? (3.14159265358979323f - a) : a;
    return copysignf(a, y);
}

// Per-triangle precompute, 5 float4 (80 B):
// q0 = (a, A)  q1 = (ab, B)  q2 = (ac, C)
// q3 = (N, 1/safe(A))  q4 = (1/safe(C), 1/safe(Cbc), 1/safe(NN), Ra_eff)
// Ra_eff (R10-validated formula): conservative radius with every reference-
// constructed q within |a-q| <= Ra_eff; slivers/degenerates blow up via the
// rNN term so the sphere screen can never exclude them.
__global__ __launch_bounds__(256) void sdf_prep_kernel(
    const int* __restrict__ faces,
    const float* __restrict__ verts,
    float4* __restrict__ pre)
{
    const int idx = blockIdx.x * 256 + threadIdx.x;   // [0, 2*NF)
    if (idx >= 2 * NF) return;
    const int m = idx >= NF ? 1 : 0;
    const int f = idx - m * NF;
    const float* __restrict__ vm = verts + m * (NV * 3);
    const int i0 = faces[3*f+0], i1 = faces[3*f+1], i2 = faces[3*f+2];
    const float ax = vm[3*i0+0], ay = vm[3*i0+1], az = vm[3*i0+2];
    const float bx = vm[3*i1+0], by = vm[3*i1+1], bz = vm[3*i1+2];
    const float cx = vm[3*i2+0], cy = vm[3*i2+1], cz = vm[3*i2+2];
    const float abx = bx - ax, aby = by - ay, abz = bz - az;
    const float acx = cx - ax, acy = cy - ay, acz = cz - az;
    const float bcx = cx - bx, bcy = cy - by, bcz = cz - bz;
    const float A   = fmaf(abx, abx, fmaf(aby, aby, abz * abz));
    const float B   = fmaf(abx, acx, fmaf(aby, acy, abz * acz));
    const float C   = fmaf(acx, acx, fmaf(acy, acy, acz * acz));
    const float Cbc = fmaf(bcx, bcx, fmaf(bcy, bcy, bcz * bcz));
    const float Nx = aby * acz - abz * acy;
    const float Ny = abz * acx - abx * acz;
    const float Nz = abx * acy - aby * acx;
    const float NN = fmaf(Nx, Nx, fmaf(Ny, Ny, Nz * Nz));
    const float rNN = 1.0f / safef(NN);
    const float sA = sqrtf(A), sC = sqrtf(C);
    const float Ra_eff = fmaf(fmaxf(sA, sC), 1.0001f,
                         fmaf(1e-3f * rNN, sA + sC, 2e-2f));
    pre[5*idx+0] = make_float4(ax, ay, az, A);
    pre[5*idx+1] = make_float4(abx, aby, abz, B);
    pre[5*idx+2] = make_float4(acx, acy, acz, C);
    pre[5*idx+3] = make_float4(Nx, Ny, Nz, 1.0f / safef(A));
    pre[5*idx+4] = make_float4(1.0f / safef(C), 1.0f / safef(Cbc), rNN, Ra_eff);
}

__global__ __launch_bounds__(256) void sdf_partial_kernel(
    const float4* __restrict__ pre,
    float* __restrict__ dmin_part,
    float2* __restrict__ zri_part,
    int* __restrict__ wnum_part)
{
    const int tid = threadIdx.x;
    const int s   = blockIdx.x & (NSPLIT - 1);
    const int pb  = blockIdx.x >> 2;          // NSPLIT == 4
    const int gp  = pb * 256 + tid;           // [0, NP)
    const int m   = gp >> 15;

    // 4x4x4 cube wave remap: lanes of one wave form a compact spatial cube so
    // the __any() screens fire together. Pure wave-composition change.
    const int cube = gp >> 6;
    const int lane = gp & 63;
    const int c9 = cube & 511;                // cube within mesh (8x8x8)
    const int cx = c9 >> 6, cy = (c9 >> 3) & 7, cz = c9 & 7;
    const int lx = lane >> 4, ly = (lane >> 2) & 3, lz = lane & 3;
    const int ix = cx * 4 + lx;
    const int iy = cy * 4 + ly;
    const int iz = cz * 4 + lz;
    const int pid = (ix << 10) | (iy << 5) | iz;

    const float px = ix * 0.0625f - 0.96875f;
    const float py = iy * 0.0625f - 0.96875f;
    const float pz = iz * 0.0625f - 0.96875f;

    // wave-uniform triangle stream (scalar loads)
    const float4* __restrict__ tp = pre + (size_t)5 * (m * NF + s * FC);

    float dmin = 3.4e38f;
    // winding as complex product: z accumulates angle mod 2pi, W counts wraps
    float zr = 1.0f, zi = 0.0f;
    int W = 0;

    auto body = [&](int k) {
        const float4 q0 = tp[5*k+0];
        const float4 q1 = tp[5*k+1];
        const float4 q2 = tp[5*k+2];
        const float4 q3 = tp[5*k+3];
        const float4 q4 = tp[5*k+4];
        const float ax = q0.x, ayy = q0.y, az = q0.z, A = q0.w;
        const float abx = q1.x, aby = q1.y, abz = q1.z, B = q1.w;
        const float acx = q2.x, acy = q2.y, acz = q2.z, C = q2.w;

        const float apx = px - ax, apy = py - ayy, apz = pz - az;
        const float papap = fmaf(apx, apx, fmaf(apy, apy, apz * apz));
        const float d1 = fmaf(abx, apx, fmaf(aby, apy, abz * apz));
        const float d2 = fmaf(acx, apx, fmaf(acy, apy, acz * apz));
        const float d4 = d2 - B;   // dot(ac,bp): winding (dbc) + distance
        const float num = -fmaf(apx, q3.x, fmaf(apy, q3.y, apz * q3.z));
        const float la = __builtin_amdgcn_sqrtf(papap);   // shared: winding+screen

        // ---------- conservative screens ----------
        // plane: dsq_ref >= num^2/max(NN,1e-12) always (every reference q is in
        //   the triangle plane; clamped rNN only lowers the bound).
        // sphere (squared form of R10's validated screen, NO serial sqrt):
        //   |a-q| <= Ra_eff  =>  dsq_ref >= (la - Ra_eff)^2 when la > Ra_eff.
        // skip safe when either bound exceeds running dmin for all lanes.
        const float D = fmaf(dmin, 1.000001f, 1e-9f);
        const float plane2 = (num * num) * q4.z;
        const float g = la - q4.w;
        const bool take = (plane2 <= D) & ((g <= 0.0f) | (g * g <= D));
        if (__any(take)) {
            // ---------- distance: EXACT R8/R3 construction (reference override
            // chain incl. barycentric fall-through quirks — do not "improve") ----
            const float d3 = d1 - A;   // dot(ab,bp)
            const float d5 = d1 - B;   // dot(ab,cp)
            const float d6 = d2 - C;   // dot(ac,cp)

            const float vc = fmaf(d1, d4, -(d3 * d2));
            const float vb = fmaf(d5, d2, -(d1 * d6));
            const float va = fmaf(d3, d6, -(d5 * d4));
            const float e1 = d4 - d3, e2 = d5 - d6;

            const bool on_bc = (va <= 0.0f) & (e1 >= 0.0f) & (e2 >= 0.0f);
            const bool on_ac = (vb <= 0.0f) & (d2 >= 0.0f) & (d6 <= 0.0f);
            const bool on_ab = (vc <= 0.0f) & (d1 >= 0.0f) & (d3 <= 0.0f);
            const bool in_c  = (d6 >= 0.0f) & (e2 <= 0.0f);
            const bool in_b  = (d3 >= 0.0f) & (e1 <= 0.0f);
            const bool in_a  = (d1 <= 0.0f) & (d2 <= 0.0f);

            float tn = on_ac ? d2 : e1;     tn = on_ab ? d1 : tn;
            float rE = on_ac ? q4.x : q4.y; rE = on_ab ? q3.w : rE;
            const float t_e = tn * rE;

            const float ssum = (va + vb) + vc;
            const float rden = __builtin_amdgcn_rcpf(safef(ssum));
            float alpha = vb * rden;
            float beta  = vc * rden;

            alpha = on_bc ? (1.0f - t_e) : alpha;  beta = (on_bc | on_ac) ? t_e : beta;
            alpha = on_ac ? 0.0f : alpha;
            alpha = on_ab ? t_e  : alpha;          beta = on_ab ? 0.0f : beta;
            alpha = in_c  ? 0.0f : alpha;          beta = in_c  ? 1.0f : beta;
            alpha = in_b  ? 1.0f : alpha;          beta = (in_b | in_a) ? 0.0f : beta;
            alpha = in_a  ? 0.0f : alpha;

            const float cqx = fmaf(beta, acx, fmaf(alpha, abx, ax));
            const float cqy = fmaf(beta, acy, fmaf(alpha, aby, ayy));
            const float cqz = fmaf(beta, acz, fmaf(alpha, abz, az));
            const float dx = px - cqx, dy = py - cqy, dz = pz - cqz;
            const float dsq = fmaf(dx, dx, fmaf(dy, dy, dz * dz));
            dmin = fminf(dmin, dsq);
        }

        // ---------- winding: bit-identical to R8/R9/R11 (identity-based) ----------
        const float pbpb = fmaf(-2.0f, d1, papap) + A;
        const float pcpc = fmaf(-2.0f, d2, papap) + C;
        const float lb = __builtin_amdgcn_sqrtf(pbpb);
        const float lc = __builtin_amdgcn_sqrtf(pcpc);
        const float dab = papap - d1;
        const float dca = papap - d2;
        const float dbc = dab - d4;
        const float den = fmaf(la * lb, lc, fmaf(dab, lc, fmaf(dbc, la, dca * lb)));

        // z *= (du, num). (0,0) -> (1,0): phi=0; num=+-0, den<0 rotates by +-pi,
        // matching atan2 convention.
        float du = den;
        if ((num == 0.0f) & (den == 0.0f)) du = 1.0f;

        const bool npos   = !__builtin_signbitf(num);  // sign of phi incl. +-0
        const bool zo_pos = (zi >= 0.0f);
        const float zr_n = fmaf(zr, du, -(zi * num));
        const float zi_n = fmaf(zr, num, zi * du);
        const bool zn_neg = (zi_n < 0.0f);
        // CCW through -x axis: +2pi ; CW through -x axis: -2pi
        W += (npos & zo_pos & zn_neg) ? 1 : 0;
        W -= ((!npos) & (!zo_pos) & (!zn_neg)) ? 1 : 0;
        zr = zr_n; zi = zi_n;
    };

    for (int k = 0; k < FC; k += 2) {
        body(k);
        body(k + 1);
        // renormalize every 2 steps (positive scale: angle & wrap state invariant)
        const float h2 = fmaf(zr, zr, zi * zi);
        const float sc = __builtin_amdgcn_rsqf(fmaxf(h2, 1e-30f));
        zr *= sc; zi *= sc;
    }

    const int gidx = s * NP + (m << 15) + pid;
    dmin_part[gidx] = dmin;
    zri_part[gidx]  = make_float2(zr, zi);
    wnum_part[gidx] = W;
}

__global__ __launch_bounds__(256) void sdf_final_kernel(
    const float* __restrict__ dmin_part,
    const float2* __restrict__ zri_part,
    const int* __restrict__ wnum_part,
    float* __restrict__ out)
{
    const int g = blockIdx.x * 256 + threadIdx.x;   // [0, NP)
    float dmin = 3.4e38f;
    double wind = 0.0;
#pragma unroll
    for (int s = 0; s < NSPLIT; ++s) {
        dmin = fminf(dmin, dmin_part[s * NP + g]);
        const float2 z = zri_part[s * NP + g];
        const int    w = wnum_part[s * NP + g];
        // per-split sum of phi = atan2 of product + 2pi * wraps (phi = omega/2)
        wind += 6.283185307179586 * (double)w + (double)atan2_fast(z.y, z.x);
    }
    const float dist = __builtin_amdgcn_sqrtf(dmin + 1e-12f);
    out[g] = (wind > 3.14159265358979323846) ? dist : 0.0f;   // sum(omega)/2 > pi
}

extern "C" void kernel_launch(void* const* d_in, const int* in_sizes, int n_in,
                              void* d_out, int out_size, void* d_ws, size_t ws_size,
                              hipStream_t stream) {
    const int*   faces = (const int*)d_in[0];
    const float* verts = (const float*)d_in[1];
    float*       out   = (float*)d_out;

    // ws: [dmin 4*65536 f32 = 1MB][zri 2MB][wnum 1MB][pre 2*13776*80B = 2.2MB]
    char* w = (char*)d_ws;
    float*  dmin_part = (float*)w;                                   w += (size_t)NSPLIT * NP * sizeof(float);
    float2* zri_part  = (float2*)w;                                  w += (size_t)NSPLIT * NP * sizeof(float2);
    int*    wnum_part = (int*)w;                                     w += (size_t)NSPLIT * NP * sizeof(int);
    float4* pre       = (float4*)w;

    sdf_prep_kernel<<<dim3((2 * NF + 255) / 256), dim3(256), 0, stream>>>(faces, verts, pre);
    sdf_partial_kernel<<<dim3((NP / 256) * NSPLIT), dim3(256), 0, stream>>>(pre, dmin_part, zri_part, wnum_part);
    sdf_final_kernel<<<dim3(NP / 256), dim3(256), 0, stream>>>(dmin_part, zri_part, wnum_part, out);
}

// Round 13
// 1826.995 us; speedup vs baseline: 1.1699x; 1.1699x over previous
//
#include <hip/hip_runtime.h>
#include <math.h>

// Problem constants: faces (13776,3) int32, vertices (2,6890,3) f32, G=32.
#define GRD 32
#define P (GRD*GRD*GRD)      // 32768 points per mesh
#define NP (2*P)             // 65536 total points
#define NV 6890
#define NF 13776
#define NSPLIT 8
#define FC (NF / NSPLIT)     // 1722 exactly (= 4*430 + 2)

__device__ __forceinline__ float safef(float x) {
    // reference _safe: |x|>1e-12 ? x : (x>=0 ? 1e-12 : -1e-12)
    float tiny = (x >= 0.0f) ? 1e-12f : -1e-12f;
    return fabsf(x) > 1e-12f ? x : tiny;
}

// precise-enough atan2 (err ~5e-7 rad), used only 16x per point in the final kernel
__device__ __forceinline__ float atan2_fast(float y, float x) {
    const float ay = fabsf(y), ax = fabsf(x);
    const float mn = fminf(ay, ax);
    const float mx = fmaxf(fmaxf(ay, ax), 1e-37f);
    const float hyp2 = fmaf(y, y, x * x);
    const float L = __builtin_amdgcn_sqrtf(hyp2);
    const float u = mn * __builtin_amdgcn_rcpf(fmaxf(mx + L, 1e-37f)); // tan(theta/2)
    const float z = u * u;
    float pl = fmaf(1.610748899076e-1f, z, -2.775537120640e-1f);
    pl = fmaf(pl, z, 3.995542129560e-1f);
    pl = fmaf(pl, z, -6.666589830780e-1f);
    float a = fmaf(pl * z, u, u + u);                 // atan(mn/mx)
    a = (ay > ax) ? (1.57079632679489662f - a) : a;
    a = (x < 0.0f) ? (3.14159265358979323f - a) : a;
    return copysignf(a, y);
}

// Per-triangle precompute, 5 float4 (80 B) — R11 layout:
// q0 = (a, A)  q1 = (ab, B)  q2 = (ac, C)
// q3 = (N, 1/safe(A))  q4 = (1/safe(C), 1/safe(Cbc), 1/safe(NN), 0)
__global__ __launch_bounds__(256) void sdf_prep_kernel(
    const int* __restrict__ faces,
    const float* __restrict__ verts,
    float4* __restrict__ pre)
{
    const int idx = blockIdx.x * 256 + threadIdx.x;   // [0, 2*NF)
    if (idx >= 2 * NF) return;
    const int m = idx >= NF ? 1 : 0;
    const int f = idx - m * NF;
    const float* __restrict__ vm = verts + m * (NV * 3);
    const int i0 = faces[3*f+0], i1 = faces[3*f+1], i2 = faces[3*f+2];
    const float ax = vm[3*i0+0], ay = vm[3*i0+1], az = vm[3*i0+2];
    const float bx = vm[3*i1+0], by = vm[3*i1+1], bz = vm[3*i1+2];
    const float cx = vm[3*i2+0], cy = vm[3*i2+1], cz = vm[3*i2+2];
    const float abx = bx - ax, aby = by - ay, abz = bz - az;
    const float acx = cx - ax, acy = cy - ay, acz = cz - az;
    const float bcx = cx - bx, bcy = cy - by, bcz = cz - bz;
    const float A   = fmaf(abx, abx, fmaf(aby, aby, abz * abz));
    const float B   = fmaf(abx, acx, fmaf(aby, acy, abz * acz));
    const float C   = fmaf(acx, acx, fmaf(acy, acy, acz * acz));
    const float Cbc = fmaf(bcx, bcx, fmaf(bcy, bcy, bcz * bcz));
    const float Nx = aby * acz - abz * acy;
    const float Ny = abz * acx - abx * acz;
    const float Nz = abx * acy - aby * acx;
    const float NN = fmaf(Nx, Nx, fmaf(Ny, Ny, Nz * Nz));
    pre[5*idx+0] = make_float4(ax, ay, az, A);
    pre[5*idx+1] = make_float4(abx, aby, abz, B);
    pre[5*idx+2] = make_float4(acx, acy, acz, C);
    pre[5*idx+3] = make_float4(Nx, Ny, Nz, 1.0f / safef(A));
    pre[5*idx+4] = make_float4(1.0f / safef(C), 1.0f / safef(Cbc), 1.0f / safef(NN), 0.0f);
}

__global__ __launch_bounds__(256) void sdf_partial_kernel(
    const float4* __restrict__ pre,
    float* __restrict__ dmin_part,
    float4* __restrict__ zri_part,
    int* __restrict__ wnum_part)
{
    const int tid = threadIdx.x;
    const int s   = blockIdx.x & (NSPLIT - 1);
    const int pb  = blockIdx.x >> 3;          // NSPLIT == 8
    const int gp  = pb * 256 + tid;           // [0, NP)
    const int m   = gp >> 15;

    // 4x4x4 cube wave remap: lanes of one wave form a compact spatial cube so
    // the __any() screen fires together. Pure wave-composition change.
    const int cube = gp >> 6;
    const int lane = gp & 63;
    const int c9 = cube & 511;                // cube within mesh (8x8x8)
    const int cx = c9 >> 6, cy = (c9 >> 3) & 7, cz = c9 & 7;
    const int lx = lane >> 4, ly = (lane >> 2) & 3, lz = lane & 3;
    const int ix = cx * 4 + lx;
    const int iy = cy * 4 + ly;
    const int iz = cz * 4 + lz;
    const int pid = (ix << 10) | (iy << 5) | iz;

    const float px = ix * 0.0625f - 0.96875f;
    const float py = iy * 0.0625f - 0.96875f;
    const float pz = iz * 0.0625f - 0.96875f;

    // wave-uniform triangle stream (scalar loads)
    const float4* __restrict__ tp = pre + (size_t)5 * (m * NF + s * FC);

    float dmin = 3.4e38f;
    // winding via TWO independent complex sub-products (even/odd triangles):
    // breaks the serial z*=w dependency chain; total phi = sum of both streams.
    float zrA = 1.0f, ziA = 0.0f, zrB = 1.0f, ziB = 0.0f;
    int WA = 0, WB = 0;

    auto body = [&](int k, float& zr, float& zi, int& W) {
        const float4 q0 = tp[5*k+0];
        const float4 q1 = tp[5*k+1];
        const float4 q2 = tp[5*k+2];
        const float4 q3 = tp[5*k+3];
        const float4 q4 = tp[5*k+4];
        const float ax = q0.x, ayy = q0.y, az = q0.z, A = q0.w;
        const float abx = q1.x, aby = q1.y, abz = q1.z, B = q1.w;
        const float acx = q2.x, acy = q2.y, acz = q2.z, C = q2.w;

        const float apx = px - ax, apy = py - ayy, apz = pz - az;
        const float papap = fmaf(apx, apx, fmaf(apy, apy, apz * apz));
        const float d1 = fmaf(abx, apx, fmaf(aby, apy, abz * apz));
        const float d2 = fmaf(acx, apx, fmaf(acy, apy, acz * apz));
        const float d4 = d2 - B;   // dot(ac,bp): winding (dbc) + distance
        const float num = -fmaf(apx, q3.x, fmaf(apy, q3.y, apz * q3.z));

        // ---------- conservative screen (plane bound only, R11) ----------
        const float plane2 = (num * num) * q4.z;
        const bool take = plane2 <= fmaf(dmin, 1.000001f, 1e-9f);
        if (__any(take)) {
            // ---------- distance: EXACT R8/R3 construction (reference override
            // chain incl. barycentric fall-through quirks — do not "improve") ----
            const float d3 = d1 - A;   // dot(ab,bp)
            const float d5 = d1 - B;   // dot(ab,cp)
            const float d6 = d2 - C;   // dot(ac,cp)

            const float vc = fmaf(d1, d4, -(d3 * d2));
            const float vb = fmaf(d5, d2, -(d1 * d6));
            const float va = fmaf(d3, d6, -(d5 * d4));
            const float e1 = d4 - d3, e2 = d5 - d6;

            const bool on_bc = (va <= 0.0f) & (e1 >= 0.0f) & (e2 >= 0.0f);
            const bool on_ac = (vb <= 0.0f) & (d2 >= 0.0f) & (d6 <= 0.0f);
            const bool on_ab = (vc <= 0.0f) & (d1 >= 0.0f) & (d3 <= 0.0f);
            const bool in_c  = (d6 >= 0.0f) & (e2 <= 0.0f);
            const bool in_b  = (d3 >= 0.0f) & (e1 <= 0.0f);
            const bool in_a  = (d1 <= 0.0f) & (d2 <= 0.0f);

            float tn = on_ac ? d2 : e1;     tn = on_ab ? d1 : tn;
            float rE = on_ac ? q4.x : q4.y; rE = on_ab ? q3.w : rE;
            const float t_e = tn * rE;

            const float ssum = (va + vb) + vc;
            const float rden = __builtin_amdgcn_rcpf(safef(ssum));
            float alpha = vb * rden;
            float beta  = vc * rden;

            alpha = on_bc ? (1.0f - t_e) : alpha;  beta = (on_bc | on_ac) ? t_e : beta;
            alpha = on_ac ? 0.0f : alpha;
            alpha = on_ab ? t_e  : alpha;          beta = on_ab ? 0.0f : beta;
            alpha = in_c  ? 0.0f : alpha;          beta = in_c  ? 1.0f : beta;
            alpha = in_b  ? 1.0f : alpha;          beta = (in_b | in_a) ? 0.0f : beta;
            alpha = in_a  ? 0.0f : alpha;

            const float cqx = fmaf(beta, acx, fmaf(alpha, abx, ax));
            const float cqy = fmaf(beta, acy, fmaf(alpha, aby, ayy));
            const float cqz = fmaf(beta, acz, fmaf(alpha, abz, az));
            const float dx = px - cqx, dy = py - cqy, dz = pz - cqz;
            const float dsq = fmaf(dx, dx, fmaf(dy, dy, dz * dz));
            dmin = fminf(dmin, dsq);
        }

        // ---------- winding (identity-based, bit-same per-triangle values) ----------
        const float pbpb = fmaf(-2.0f, d1, papap) + A;
        const float pcpc = fmaf(-2.0f, d2, papap) + C;
        const float la = __builtin_amdgcn_sqrtf(papap);
        const float lb = __builtin_amdgcn_sqrtf(pbpb);
        const float lc = __builtin_amdgcn_sqrtf(pcpc);
        const float dab = papap - d1;
        const float dca = papap - d2;
        const float dbc = dab - d4;
        const float den = fmaf(la * lb, lc, fmaf(dab, lc, fmaf(dbc, la, dca * lb)));

        // z *= (du, num). (0,0) -> (1,0): phi=0; num=+-0, den<0 rotates by +-pi.
        float du = den;
        if ((num == 0.0f) & (den == 0.0f)) du = 1.0f;

        const bool npos   = !__builtin_signbitf(num);  // sign of phi incl. +-0
        const bool zo_pos = (zi >= 0.0f);
        const float zr_n = fmaf(zr, du, -(zi * num));
        const float zi_n = fmaf(zr, num, zi * du);
        const bool zn_neg = (zi_n < 0.0f);
        // CCW through -x axis: +2pi ; CW through -x axis: -2pi
        W += (npos & zo_pos & zn_neg) ? 1 : 0;
        W -= ((!npos) & (!zo_pos) & (!zn_neg)) ? 1 : 0;
        zr = zr_n; zi = zi_n;
    };

    auto renorm = [&](float& zr, float& zi) {
        // positive scale: angle & wrap state invariant; keeps |z| in normal range
        const float h2 = fmaf(zr, zr, zi * zi);
        const float sc = __builtin_amdgcn_rsqf(fmaxf(h2, 1e-30f));
        zr *= sc; zi *= sc;
    };

    int k = 0;
    for (; k + 4 <= FC; k += 4) {             // 430 iterations
        body(k + 0, zrA, ziA, WA);
        body(k + 1, zrB, ziB, WB);
        body(k + 2, zrA, ziA, WA);
        body(k + 3, zrB, ziB, WB);
        renorm(zrA, ziA);
        renorm(zrB, ziB);
    }
    for (; k < FC; k += 2) {                  // tail: 2 triangles
        body(k + 0, zrA, ziA, WA);
        body(k + 1, zrB, ziB, WB);
        renorm(zrA, ziA);
        renorm(zrB, ziB);
    }

    const int gidx = s * NP + (m << 15) + pid;
    dmin_part[gidx] = dmin;
    zri_part[gidx]  = make_float4(zrA, ziA, zrB, ziB);
    wnum_part[gidx] = WA + WB;
}

__global__ __launch_bounds__(256) void sdf_final_kernel(
    const float* __restrict__ dmin_part,
    const float4* __restrict__ zri_part,
    const int* __restrict__ wnum_part,
    float* __restrict__ out)
{
    const int g = blockIdx.x * 256 + threadIdx.x;   // [0, NP)
    float dmin = 3.4e38f;
    double wind = 0.0;
#pragma unroll
    for (int s = 0; s < NSPLIT; ++s) {
        dmin = fminf(dmin, dmin_part[s * NP + g]);
        const float4 z = zri_part[s * NP + g];
        const int    w = wnum_part[s * NP + g];
        // per-split sum of phi = atan2 of both sub-products + 2pi * total wraps
        wind += 6.283185307179586 * (double)w
              + (double)atan2_fast(z.y, z.x)
              + (double)atan2_fast(z.w, z.z);
    }
    const float dist = __builtin_amdgcn_sqrtf(dmin + 1e-12f);
    out[g] = (wind > 3.14159265358979323846) ? dist : 0.0f;   // sum(omega)/2 > pi
}

extern "C" void kernel_launch(void* const* d_in, const int* in_sizes, int n_in,
                              void* d_out, int out_size, void* d_ws, size_t ws_size,
                              hipStream_t stream) {
    const int*   faces = (const int*)d_in[0];
    const float* verts = (const float*)d_in[1];
    float*       out   = (float*)d_out;

    // ws: [dmin 8*65536 f32 = 2MB][zri 8*65536 f32x4 = 8MB][wnum 2MB][pre 2.2MB]
    char* w = (char*)d_ws;
    float*  dmin_part = (float*)w;                                   w += (size_t)NSPLIT * NP * sizeof(float);
    float4* zri_part  = (float4*)w;                                  w += (size_t)NSPLIT * NP * sizeof(float4);
    int*    wnum_part = (int*)w;                                     w += (size_t)NSPLIT * NP * sizeof(int);
    float4* pre       = (float4*)w;

    sdf_prep_kernel<<<dim3((2 * NF + 255) / 256), dim3(256), 0, stream>>>(faces, verts, pre);
    sdf_partial_kernel<<<dim3((NP / 256) * NSPLIT), dim3(256), 0, stream>>>(pre, dmin_part, zri_part, wnum_part);
    sdf_final_kernel<<<dim3(NP / 256), dim3(256), 0, stream>>>(dmin_part, zri_part, wnum_part, out);
}

// Round 14
// 1824.998 us; speedup vs baseline: 1.1711x; 1.0011x over previous
//
#include <hip/hip_runtime.h>
#include <math.h>

// Problem constants: faces (13776,3) int32, vertices (2,6890,3) f32, G=32.
#define GRD 32
#define P (GRD*GRD*GRD)      // 32768 points per mesh
#define NP (2*P)             // 65536 total points
#define NV 6890
#define NF 13776
#define NSPLIT 8
#define FC (NF / NSPLIT)     // 1722 exactly (= 4*430 + 2)

__device__ __forceinline__ float safef(float x) {
    // reference _safe: |x|>1e-12 ? x : (x>=0 ? 1e-12 : -1e-12)
    float tiny = (x >= 0.0f) ? 1e-12f : -1e-12f;
    return fabsf(x) > 1e-12f ? x : tiny;
}

// precise-enough atan2 (err ~5e-7 rad), used only 8x per point in the final kernel
__device__ __forceinline__ float atan2_fast(float y, float x) {
    const float ay = fabsf(y), ax = fabsf(x);
    const float mn = fminf(ay, ax);
    const float mx = fmaxf(fmaxf(ay, ax), 1e-37f);
    const float hyp2 = fmaf(y, y, x * x);
    const float L = __builtin_amdgcn_sqrtf(hyp2);
    const float u = mn * __builtin_amdgcn_rcpf(fmaxf(mx + L, 1e-37f)); // tan(theta/2)
    const float z = u * u;
    float pl = fmaf(1.610748899076e-1f, z, -2.775537120640e-1f);
    pl = fmaf(pl, z, 3.995542129560e-1f);
    pl = fmaf(pl, z, -6.666589830780e-1f);
    float a = fmaf(pl * z, u, u + u);                 // atan(mn/mx)
    a = (ay > ax) ? (1.57079632679489662f - a) : a;
    a = (x < 0.0f) ? (3.14159265358979323f - a) : a;
    return copysignf(a, y);
}

// Per-triangle precompute, 5 float4 (80 B) — R11 layout:
// q0 = (a, A)  q1 = (ab, B)  q2 = (ac, C)
// q3 = (N, 1/safe(A))  q4 = (1/safe(C), 1/safe(Cbc), 1/safe(NN), 0)
__global__ __launch_bounds__(256) void sdf_prep_kernel(
    const int* __restrict__ faces,
    const float* __restrict__ verts,
    float4* __restrict__ pre)
{
    const int idx = blockIdx.x * 256 + threadIdx.x;   // [0, 2*NF)
    if (idx >= 2 * NF) return;
    const int m = idx >= NF ? 1 : 0;
    const int f = idx - m * NF;
    const float* __restrict__ vm = verts + m * (NV * 3);
    const int i0 = faces[3*f+0], i1 = faces[3*f+1], i2 = faces[3*f+2];
    const float ax = vm[3*i0+0], ay = vm[3*i0+1], az = vm[3*i0+2];
    const float bx = vm[3*i1+0], by = vm[3*i1+1], bz = vm[3*i1+2];
    const float cx = vm[3*i2+0], cy = vm[3*i2+1], cz = vm[3*i2+2];
    const float abx = bx - ax, aby = by - ay, abz = bz - az;
    const float acx = cx - ax, acy = cy - ay, acz = cz - az;
    const float bcx = cx - bx, bcy = cy - by, bcz = cz - bz;
    const float A   = fmaf(abx, abx, fmaf(aby, aby, abz * abz));
    const float B   = fmaf(abx, acx, fmaf(aby, acy, abz * acz));
    const float C   = fmaf(acx, acx, fmaf(acy, acy, acz * acz));
    const float Cbc = fmaf(bcx, bcx, fmaf(bcy, bcy, bcz * bcz));
    const float Nx = aby * acz - abz * acy;
    const float Ny = abz * acx - abx * acz;
    const float Nz = abx * acy - aby * acx;
    const float NN = fmaf(Nx, Nx, fmaf(Ny, Ny, Nz * Nz));
    pre[5*idx+0] = make_float4(ax, ay, az, A);
    pre[5*idx+1] = make_float4(abx, aby, abz, B);
    pre[5*idx+2] = make_float4(acx, acy, acz, C);
    pre[5*idx+3] = make_float4(Nx, Ny, Nz, 1.0f / safef(A));
    pre[5*idx+4] = make_float4(1.0f / safef(C), 1.0f / safef(Cbc), 1.0f / safef(NN), 0.0f);
}

__global__ __launch_bounds__(256) void sdf_partial_kernel(
    const float4* __restrict__ pre,
    float* __restrict__ dmin_part,
    float2* __restrict__ zri_part,
    int* __restrict__ wnum_part)
{
    const int tid = threadIdx.x;
    const int s   = blockIdx.x & (NSPLIT - 1);
    const int pb  = blockIdx.x >> 3;          // NSPLIT == 8
    const int gp  = pb * 256 + tid;           // [0, NP)
    const int m   = gp >> 15;

    // 4x4x4 cube wave remap: lanes of one wave form a compact spatial cube so
    // the __any() screen fires together. Pure wave-composition change.
    const int cube = gp >> 6;
    const int lane = gp & 63;
    const int c9 = cube & 511;                // cube within mesh (8x8x8)
    const int cx = c9 >> 6, cy = (c9 >> 3) & 7, cz = c9 & 7;
    const int lx = lane >> 4, ly = (lane >> 2) & 3, lz = lane & 3;
    const int ix = cx * 4 + lx;
    const int iy = cy * 4 + ly;
    const int iz = cz * 4 + lz;
    const int pid = (ix << 10) | (iy << 5) | iz;

    const float px = ix * 0.0625f - 0.96875f;
    const float py = iy * 0.0625f - 0.96875f;
    const float pz = iz * 0.0625f - 0.96875f;

    // wave-uniform triangle stream (scalar loads)
    const float4* __restrict__ tp = pre + (size_t)5 * (m * NF + s * FC);

    // ---------- a-priori dmin upper bound (screen seed) ----------
    // UB = min over sampled HEALTHY triangles of |p - a|^2 (inflated). For a
    // healthy triangle (rNN < 1e3 i.e. NN > 1e-3) the reference q is the true
    // closest point, so |p-a|^2 >= dsq_ref >= global min. UB only feeds the
    // screen; the stored dmin is min-of-processed-dsq -> final result bit-exact.
    float UB = 3.4e38f;
    for (int j = 0; j < 16; ++j) {
        const int k = j * 107;                // spread across this split's 1722
        const float4 s0 = tp[5*k+0];
        const float4 s4 = tp[5*k+4];
        const float vx = px - s0.x, vy = py - s0.y, vzf = pz - s0.z;
        const float dv = fmaf(vx, vx, fmaf(vy, vy, vzf * vzf));
        const float ub = fmaf(dv, 1.0001f, 1e-5f);
        UB = (s4.z < 1e3f) ? fminf(UB, ub) : UB;
    }

    float dmin  = 3.4e38f;                    // true min of processed dsq (stored)
    float dscr  = UB;                         // screen bound = min(UB, dmin)
    // winding as complex product: z accumulates angle mod 2pi, W counts wraps
    float zr = 1.0f, zi = 0.0f;
    int W = 0;

    auto body = [&](int k) {
        const float4 q0 = tp[5*k+0];
        const float4 q1 = tp[5*k+1];
        const float4 q2 = tp[5*k+2];
        const float4 q3 = tp[5*k+3];
        const float4 q4 = tp[5*k+4];
        const float ax = q0.x, ayy = q0.y, az = q0.z, A = q0.w;
        const float abx = q1.x, aby = q1.y, abz = q1.z, B = q1.w;
        const float acx = q2.x, acy = q2.y, acz = q2.z, C = q2.w;

        const float apx = px - ax, apy = py - ayy, apz = pz - az;
        const float papap = fmaf(apx, apx, fmaf(apy, apy, apz * apz));
        const float d1 = fmaf(abx, apx, fmaf(aby, apy, abz * apz));
        const float d2 = fmaf(acx, apx, fmaf(acy, apy, acz * apz));
        const float d4 = d2 - B;   // dot(ac,bp): winding (dbc) + distance
        const float num = -fmaf(apx, q3.x, fmaf(apy, q3.y, apz * q3.z));

        // ---------- conservative screen (plane bound vs seeded dscr) ----------
        const float plane2 = (num * num) * q4.z;
        const bool take = plane2 <= fmaf(dscr, 1.000001f, 1e-9f);
        if (__any(take)) {
            // ---------- distance: EXACT R8/R3 construction (reference override
            // chain incl. barycentric fall-through quirks — do not "improve") ----
            const float d3 = d1 - A;   // dot(ab,bp)
            const float d5 = d1 - B;   // dot(ab,cp)
            const float d6 = d2 - C;   // dot(ac,cp)

            const float vc = fmaf(d1, d4, -(d3 * d2));
            const float vb = fmaf(d5, d2, -(d1 * d6));
            const float va = fmaf(d3, d6, -(d5 * d4));
            const float e1 = d4 - d3, e2 = d5 - d6;

            const bool on_bc = (va <= 0.0f) & (e1 >= 0.0f) & (e2 >= 0.0f);
            const bool on_ac = (vb <= 0.0f) & (d2 >= 0.0f) & (d6 <= 0.0f);
            const bool on_ab = (vc <= 0.0f) & (d1 >= 0.0f) & (d3 <= 0.0f);
            const bool in_c  = (d6 >= 0.0f) & (e2 <= 0.0f);
            const bool in_b  = (d3 >= 0.0f) & (e1 <= 0.0f);
            const bool in_a  = (d1 <= 0.0f) & (d2 <= 0.0f);

            float tn = on_ac ? d2 : e1;     tn = on_ab ? d1 : tn;
            float rE = on_ac ? q4.x : q4.y; rE = on_ab ? q3.w : rE;
            const float t_e = tn * rE;

            const float ssum = (va + vb) + vc;
            const float rden = __builtin_amdgcn_rcpf(safef(ssum));
            float alpha = vb * rden;
            float beta  = vc * rden;

            alpha = on_bc ? (1.0f - t_e) : alpha;  beta = (on_bc | on_ac) ? t_e : beta;
            alpha = on_ac ? 0.0f : alpha;
            alpha = on_ab ? t_e  : alpha;          beta = on_ab ? 0.0f : beta;
            alpha = in_c  ? 0.0f : alpha;          beta = in_c  ? 1.0f : beta;
            alpha = in_b  ? 1.0f : alpha;          beta = (in_b | in_a) ? 0.0f : beta;
            alpha = in_a  ? 0.0f : alpha;

            const float cqx = fmaf(beta, acx, fmaf(alpha, abx, ax));
            const float cqy = fmaf(beta, acy, fmaf(alpha, aby, ayy));
            const float cqz = fmaf(beta, acz, fmaf(alpha, abz, az));
            const float dx = px - cqx, dy = py - cqy, dz = pz - cqz;
            const float dsq = fmaf(dx, dx, fmaf(dy, dy, dz * dz));
            dmin = fminf(dmin, dsq);
            dscr = fminf(dscr, dsq);
        }

        // ---------- winding: bit-identical to R8/R11 (identity-based) ----------
        const float pbpb = fmaf(-2.0f, d1, papap) + A;
        const float pcpc = fmaf(-2.0f, d2, papap) + C;
        const float la = __builtin_amdgcn_sqrtf(papap);
        const float lb = __builtin_amdgcn_sqrtf(pbpb);
        const float lc = __builtin_amdgcn_sqrtf(pcpc);
        const float dab = papap - d1;
        const float dca = papap - d2;
        const float dbc = dab - d4;
        const float den = fmaf(la * lb, lc, fmaf(dab, lc, fmaf(dbc, la, dca * lb)));

        // z *= (du, num). (0,0) -> (1,0): phi=0; num=+-0, den<0 rotates by +-pi,
        // matching atan2 convention.
        float du = den;
        if ((num == 0.0f) & (den == 0.0f)) du = 1.0f;

        const bool npos   = !__builtin_signbitf(num);  // sign of phi incl. +-0
        const bool zo_pos = (zi >= 0.0f);
        const float zr_n = fmaf(zr, du, -(zi * num));
        const float zi_n = fmaf(zr, num, zi * du);
        const bool zn_neg = (zi_n < 0.0f);
        // CCW through -x axis: +2pi ; CW through -x axis: -2pi
        W += (npos & zo_pos & zn_neg) ? 1 : 0;
        W -= ((!npos) & (!zo_pos) & (!zn_neg)) ? 1 : 0;
        zr = zr_n; zi = zi_n;
    };

    auto renorm = [&]() {
        // positive scale: angle & wrap state invariant; keeps |z| in normal range.
        // every-4 safe: |w| in [~1e-6, ~1.1e3] -> |z| in [1e-24, 1.5e12].
        const float h2 = fmaf(zr, zr, zi * zi);
        const float sc = __builtin_amdgcn_rsqf(fmaxf(h2, 1e-30f));
        zr *= sc; zi *= sc;
    };

    int k = 0;
    for (; k + 4 <= FC; k += 4) {             // 430 iterations
        body(k + 0);
        body(k + 1);
        body(k + 2);
        body(k + 3);
        renorm();
    }
    for (; k < FC; ++k) body(k);              // tail: 2 triangles
    renorm();

    const int gidx = s * NP + (m << 15) + pid;
    dmin_part[gidx] = dmin;
    zri_part[gidx]  = make_float2(zr, zi);
    wnum_part[gidx] = W;
}

__global__ __launch_bounds__(256) void sdf_final_kernel(
    const float* __restrict__ dmin_part,
    const float2* __restrict__ zri_part,
    const int* __restrict__ wnum_part,
    float* __restrict__ out)
{
    const int g = blockIdx.x * 256 + threadIdx.x;   // [0, NP)
    float dmin = 3.4e38f;
    double wind = 0.0;
#pragma unroll
    for (int s = 0; s < NSPLIT; ++s) {
        dmin = fminf(dmin, dmin_part[s * NP + g]);
        const float2 z = zri_part[s * NP + g];
        const int    w = wnum_part[s * NP + g];
        // per-split sum of phi = atan2 of product + 2pi * wraps (phi = omega/2)
        wind += 6.283185307179586 * (double)w + (double)atan2_fast(z.y, z.x);
    }
    const float dist = __builtin_amdgcn_sqrtf(dmin + 1e-12f);
    out[g] = (wind > 3.14159265358979323846) ? dist : 0.0f;   // sum(omega)/2 > pi
}

extern "C" void kernel_launch(void* const* d_in, const int* in_sizes, int n_in,
                              void* d_out, int out_size, void* d_ws, size_t ws_size,
                              hipStream_t stream) {
    const int*   faces = (const int*)d_in[0];
    const float* verts = (const float*)d_in[1];
    float*       out   = (float*)d_out;

    // ws: [dmin 2MB][zri 4MB][wnum 2MB][pre 2*13776*80B = 2.2MB]
    char* w = (char*)d_ws;
    float*  dmin_part = (float*)w;                                   w += (size_t)NSPLIT * NP * sizeof(float);
    float2* zri_part  = (float2*)w;                                  w += (size_t)NSPLIT * NP * sizeof(float2);
    int*    wnum_part = (int*)w;                                     w += (size_t)NSPLIT * NP * sizeof(int);
    float4* pre       = (float4*)w;

    sdf_prep_kernel<<<dim3((2 * NF + 255) / 256), dim3(256), 0, stream>>>(faces, verts, pre);
    sdf_partial_kernel<<<dim3((NP / 256) * NSPLIT), dim3(256), 0, stream>>>(pre, dmin_part, zri_part, wnum_part);
    sdf_final_kernel<<<dim3(NP / 256), dim3(256), 0, stream>>>(dmin_part, zri_part, wnum_part, out);
}